// Round 5
// baseline (139.128 us; speedup 1.0000x reference)
//
#include <hip/hip_runtime.h>
#include <hip/hip_cooperative_groups.h>
#include <math.h>

namespace cg = cooperative_groups;

#define NB 8
#define N_OP 1000
#define N_MA 64
#define IN_SRC 128
#define IN_DST 64
#define DD 128
#define NEG_SLOPE 0.2f
#define TILE_O 32
#define NTILE 32
#define HPAD 132   // 32-row tile padded stride (kills 8-way bank conflict)

__device__ __forceinline__ float lrelu(float x) { return x >= 0.f ? x : NEG_SLOPE * x; }

__device__ __forceinline__ float wave_sum(float v) {
    for (int off = 32; off; off >>= 1) v += __shfl_xor(v, off, 64);
    return v;
}

// ---------------- fused cooperative kernel ----------------
struct ABShared {
    float H[TILE_O][HPAD];     // 16.9 KB
    float P[TILE_O][N_MA];     // 8 KB
    float u[DD];
    float el[TILE_O];
    float redz[4][N_MA];
    float redse[4][N_MA];
};
struct CShared {
    float S[2][DD];
    float Z[2], SE[2];
};
union SharedU { ABShared ab; CShared c; };

__global__ __launch_bounds__(256) void fused_all(
    const float* __restrict__ h_src, const float* __restrict__ h_dst,
    const float* __restrict__ edge_feat, const int* __restrict__ adj,
    const float* __restrict__ W_src, const float* __restrict__ W_dst,
    const float* __restrict__ W_edge, const float* __restrict__ attn_l,
    const float* __restrict__ attn_r, float* __restrict__ out,
    float* __restrict__ u, float* __restrict__ c_we, float* __restrict__ er,
    float* __restrict__ feat_dst, float* __restrict__ zpart,
    float* __restrict__ separt, float* __restrict__ S_part) {
    __shared__ SharedU sh;
    cg::grid_group grid = cg::this_grid();

    int blk = blockIdx.x;               // 256 blocks
    int b = blk >> 5, ti = blk & 31;
    int o0 = ti * TILE_O;
    int nrows = min(TILE_O, N_OP - o0); // 32 (8 for ti==31)
    int t = threadIdx.x;
    int lane = t & 63, w = t >> 6;

    // ---------------- Stage A ----------------
    // A1: every block stages its H tile (coalesced float4, OOB rows zeroed)
    #pragma unroll
    for (int c = 0; c < 4; ++c) {
        int flat = c * 256 + t;          // 1024 float4 slots = 32 rows x 32
        int row = flat >> 5, col = (flat & 31) * 4;
        float4 hv = make_float4(0.f, 0.f, 0.f, 0.f);
        if (row < nrows)
            hv = *reinterpret_cast<const float4*>(
                h_src + ((size_t)(b * N_OP + o0 + row) * DD + col));
        *reinterpret_cast<float4*>(&sh.ab.H[row][col]) = hv;
    }

    // A2: side tasks distributed by block id
    if (blk < 32) {                      // u rows: one per wave
        int row = blk * 4 + w;           // < 128
        float al0 = attn_l[lane], al1 = attn_l[lane + 64];
        float part = W_src[row * DD + lane] * al0 +
                     W_src[row * DD + lane + 64] * al1;
        part = wave_sum(part);
        if (lane == 0) u[row] = part;
    } else if (blk == 32) {
        if (w == 0) {
            float part = W_edge[lane] * attn_l[lane] +
                         W_edge[lane + 64] * attn_l[lane + 64];
            part = wave_sum(part);
            if (lane == 0) c_we[0] = part;
        }
    } else if (blk >= 64 && blk < 192) { // feat_dst + er: one row per wave
        int bm = (blk - 64) * 4 + w;     // < 512
        const float* h = h_dst + (size_t)bm * IN_DST;
        float ar0 = attn_r[lane], ar1 = attn_r[lane + 64];
        float a0 = 0.f, a1 = 0.f;
        #pragma unroll 8
        for (int k = 0; k < IN_DST; ++k) {
            float hk = h[k];
            a0 += hk * W_dst[k * DD + lane];
            a1 += hk * W_dst[k * DD + lane + 64];
        }
        feat_dst[(size_t)bm * DD + lane] = a0;
        feat_dst[(size_t)bm * DD + lane + 64] = a1;
        float r = a0 * ar0 + a1 * ar1;
        r = wave_sum(r);
        if (lane == 0) er[bm] = r;
    }

    __threadfence();
    grid.sync();

    // ---------------- Stage B ----------------
    float cwe = c_we[0];
    if (t < DD) sh.ab.u[t] = u[t];
    __syncthreads();

    // el for the block's 32 rows: thread t -> row t>>3, 8-lane-group reduce
    {
        int r = t >> 3, sub = t & 7;
        float part = 0.f;
        #pragma unroll
        for (int q = 0; q < 16; ++q)
            part += sh.ab.H[r][sub + 8 * q] * sh.ab.u[sub + 8 * q];
        part += __shfl_xor(part, 1, 64);
        part += __shfl_xor(part, 2, 64);
        part += __shfl_xor(part, 4, 64);
        if (sub == 0) sh.ab.el[r] = part;
    }
    __syncthreads();

    // phase 1: p + tile stats (coalesced adj/ef rows)
    {
        int m = lane, og = w;
        float er_bm = er[b * N_MA + m];
        float z = 0.f, se = 0.f;
        for (int r = og; r < TILE_O; r += 4) {
            float p = 0.f;
            if (r < nrows) {
                size_t e = (size_t)(b * N_OP + o0 + r) * N_MA + m;
                if (adj[e]) {
                    float ef = edge_feat[e];
                    float vv = lrelu(sh.ab.el[r] + er_bm + ef * cwe);
                    p = __expf(vv);
                    z += p;
                    se += p * ef;
                }
            }
            sh.ab.P[r][m] = p;
        }
        sh.ab.redz[og][m] = z;
        sh.ab.redse[og][m] = se;
    }
    __syncthreads();

    if (t < 64) {
        zpart[ti * 512 + b * N_MA + t] =
            sh.ab.redz[0][t] + sh.ab.redz[1][t] + sh.ab.redz[2][t] + sh.ab.redz[3][t];
    } else if (t < 128) {
        int mm = t - 64;
        separt[ti * 512 + b * N_MA + mm] =
            sh.ab.redse[0][mm] + sh.ab.redse[1][mm] + sh.ab.redse[2][mm] + sh.ab.redse[3][mm];
    }

    // phase 2: S_part[m][i] = sum_k P[k][m] * H[k][i]
    {
        int i4 = t & 31, mg = t >> 5;
        float acc[8][4];
        #pragma unroll
        for (int a = 0; a < 8; ++a)
            #pragma unroll
            for (int c = 0; c < 4; ++c) acc[a][c] = 0.f;

        for (int k = 0; k < TILE_O; ++k) {
            float4 hv = *reinterpret_cast<const float4*>(&sh.ab.H[k][i4 * 4]);
            float4 pa = *reinterpret_cast<const float4*>(&sh.ab.P[k][mg * 8]);
            float4 pb = *reinterpret_cast<const float4*>(&sh.ab.P[k][mg * 8 + 4]);
            float hh[4] = {hv.x, hv.y, hv.z, hv.w};
            float pp[8] = {pa.x, pa.y, pa.z, pa.w, pb.x, pb.y, pb.z, pb.w};
            #pragma unroll
            for (int mm = 0; mm < 8; ++mm)
                #pragma unroll
                for (int ii = 0; ii < 4; ++ii)
                    acc[mm][ii] += pp[mm] * hh[ii];
        }
        #pragma unroll
        for (int mm = 0; mm < 8; ++mm) {
            size_t off = ((size_t)(b * NTILE + ti) * N_MA + mg * 8 + mm) * DD + i4 * 4;
            *reinterpret_cast<float4*>(S_part + off) =
                make_float4(acc[mm][0], acc[mm][1], acc[mm][2], acc[mm][3]);
        }
    }

    __threadfence();
    grid.sync();

    // ---------------- Stage C: 2 (b,m) pairs per block, in parallel ----------------
    {
        int g = t >> 7;                  // pair slot 0/1
        int i = t & 127;
        int bm = blk * 2 + g;            // < 512
        int b_c = bm >> 6, m_c = bm & 63;
        int wv = (t >> 6) & 1;

        if (wv == 0) {
            float v = (lane < NTILE) ? zpart[lane * 512 + bm] : 0.f;
            v = wave_sum(v);
            if (lane == 0) sh.c.Z[g] = v;
        } else {
            float v = (lane < NTILE) ? separt[lane * 512 + bm] : 0.f;
            v = wave_sum(v);
            if (lane == 0) sh.c.SE[g] = v;
        }

        float ps = 0.f;
        #pragma unroll 4
        for (int tt = 0; tt < NTILE; ++tt)
            ps += S_part[((size_t)(b_c * NTILE + tt) * N_MA + m_c) * DD + i];
        sh.c.S[g][i] = ps;
        __syncthreads();

        float acc = 0.f;
        #pragma unroll 8
        for (int ii = 0; ii < DD; ++ii) acc += sh.c.S[g][ii] * W_src[ii * DD + i];

        float er_bm = er[bm];
        float p_kk = __expf(lrelu(2.f * er_bm));
        float Z = sh.c.Z[g] + p_kk;
        float invZ = 1.f / Z;
        float val = W_edge[i] * (sh.c.SE[g] * invZ) + acc * invZ +
                    feat_dst[(size_t)bm * DD + i] * (p_kk * invZ);
        out[(size_t)bm * DD + i] = 1.f / (1.f + __expf(-val));
    }
}

// ---------------- fallback path (proven R4 kernels) ----------------
__global__ __launch_bounds__(256) void prep_par(
    const float* __restrict__ W_src, const float* __restrict__ W_edge,
    const float* __restrict__ attn_l, float* __restrict__ u,
    float* __restrict__ c_we) {
    int lane = threadIdx.x & 63;
    int task = blockIdx.x * 4 + (threadIdx.x >> 6);
    float al0 = attn_l[lane], al1 = attn_l[lane + 64];
    if (task < 128) {
        float part = W_src[task * DD + lane] * al0 + W_src[task * DD + lane + 64] * al1;
        part = wave_sum(part);
        if (lane == 0) u[task] = part;
    } else if (task == 128) {
        float part = W_edge[lane] * al0 + W_edge[lane + 64] * al1;
        part = wave_sum(part);
        if (lane == 0) c_we[0] = part;
    }
}

__global__ __launch_bounds__(256) void elfdst_kernel(
    const float* __restrict__ h_src, const float* __restrict__ u,
    const float* __restrict__ h_dst, const float* __restrict__ W_dst,
    const float* __restrict__ attn_r, float* __restrict__ el,
    float* __restrict__ feat_dst, float* __restrict__ er) {
    int blk = blockIdx.x;
    int lane = threadIdx.x & 63;
    int w = threadIdx.x >> 6;
    if (blk < 2000) {
        int row = blk * 4 + w;
        const float* h = h_src + (size_t)row * IN_SRC;
        float acc = h[lane] * u[lane] + h[lane + 64] * u[lane + 64];
        acc = wave_sum(acc);
        if (lane == 0) el[row] = acc;
    } else {
        int bm = (blk - 2000) * 4 + w;
        const float* h = h_dst + (size_t)bm * IN_DST;
        float a0 = 0.f, a1 = 0.f;
        #pragma unroll 8
        for (int k = 0; k < IN_DST; ++k) {
            float hk = h[k];
            a0 += hk * W_dst[k * DD + lane];
            a1 += hk * W_dst[k * DD + lane + 64];
        }
        feat_dst[(size_t)bm * DD + lane] = a0;
        feat_dst[(size_t)bm * DD + lane + 64] = a1;
        float r = a0 * attn_r[lane] + a1 * attn_r[lane + 64];
        r = wave_sum(r);
        if (lane == 0) er[bm] = r;
    }
}

__global__ __launch_bounds__(256) void ab_kernel(
    const float* __restrict__ edge_feat, const int* __restrict__ adj,
    const float* __restrict__ h_src, const float* __restrict__ el,
    const float* __restrict__ er, const float* __restrict__ c_we_p,
    float* __restrict__ S_part, float* __restrict__ zpart,
    float* __restrict__ separt) {
    __shared__ float P_l[TILE_O][N_MA];
    __shared__ float H_l[TILE_O][DD];
    __shared__ float redz[4][64], redse[4][64];

    int blk = blockIdx.x;
    int b = blk >> 5, ti = blk & 31;
    int o0 = ti * TILE_O;
    int nrows = min(TILE_O, N_OP - o0);
    int t = threadIdx.x;
    float cwe = c_we_p[0];

    #pragma unroll
    for (int c = 0; c < 4; ++c) {
        int flat = c * 256 + t;
        int row = flat >> 5, col = (flat & 31) * 4;
        float4 hv = make_float4(0.f, 0.f, 0.f, 0.f);
        if (row < nrows)
            hv = *reinterpret_cast<const float4*>(
                h_src + ((size_t)(b * N_OP + o0 + row) * DD + col));
        *reinterpret_cast<float4*>(&H_l[row][col]) = hv;
    }

    int m = t & 63, og = t >> 6;
    float er_bm = er[b * N_MA + m];
    float z = 0.f, se = 0.f;
    for (int r = og; r < TILE_O; r += 4) {
        float p = 0.f;
        if (r < nrows) {
            int o = o0 + r;
            size_t eidx = (size_t)(b * N_OP + o) * N_MA + m;
            if (adj[eidx]) {
                float efv = edge_feat[eidx];
                float v = lrelu(el[b * N_OP + o] + er_bm + efv * cwe);
                p = __expf(v);
                z += p;
                se += p * efv;
            }
        }
        P_l[r][m] = p;
    }
    redz[og][m] = z;
    redse[og][m] = se;
    __syncthreads();

    if (t < 64) {
        zpart[ti * 512 + b * N_MA + t] =
            redz[0][t] + redz[1][t] + redz[2][t] + redz[3][t];
    } else if (t < 128) {
        int mm = t - 64;
        separt[ti * 512 + b * N_MA + mm] =
            redse[0][mm] + redse[1][mm] + redse[2][mm] + redse[3][mm];
    }

    int i4 = t & 31, mg = t >> 5;
    float acc[8][4];
    #pragma unroll
    for (int a = 0; a < 8; ++a)
        #pragma unroll
        for (int c = 0; c < 4; ++c) acc[a][c] = 0.f;

    for (int k = 0; k < TILE_O; ++k) {
        float4 hv = *reinterpret_cast<const float4*>(&H_l[k][i4 * 4]);
        float4 pa = *reinterpret_cast<const float4*>(&P_l[k][mg * 8]);
        float4 pb = *reinterpret_cast<const float4*>(&P_l[k][mg * 8 + 4]);
        float hh[4] = {hv.x, hv.y, hv.z, hv.w};
        float pp[8] = {pa.x, pa.y, pa.z, pa.w, pb.x, pb.y, pb.z, pb.w};
        #pragma unroll
        for (int mm = 0; mm < 8; ++mm)
            #pragma unroll
            for (int ii = 0; ii < 4; ++ii)
                acc[mm][ii] += pp[mm] * hh[ii];
    }

    #pragma unroll
    for (int mm = 0; mm < 8; ++mm) {
        size_t off = ((size_t)(b * NTILE + ti) * N_MA + mg * 8 + mm) * DD + i4 * 4;
        *reinterpret_cast<float4*>(S_part + off) =
            make_float4(acc[mm][0], acc[mm][1], acc[mm][2], acc[mm][3]);
    }
}

__global__ __launch_bounds__(256) void c_kernel(
    const float* __restrict__ S_part, const float* __restrict__ zpart,
    const float* __restrict__ separt, const float* __restrict__ er,
    const float* __restrict__ feat_dst, const float* __restrict__ W_src,
    const float* __restrict__ W_edge, float* __restrict__ out) {
    __shared__ float Sp[2][DD];
    __shared__ float S_l[DD];
    __shared__ float Wp[2][DD];
    __shared__ float sZ, sSE;

    int bm = blockIdx.x;
    int b = bm >> 6, m = bm & 63;
    int t = threadIdx.x;
    int i = t & 127, h = t >> 7;
    int lane = t & 63, w = t >> 6;

    if (w == 0) {
        float v = (lane < NTILE) ? zpart[lane * 512 + bm] : 0.f;
        v = wave_sum(v);
        if (lane == 0) sZ = v;
    } else if (w == 1) {
        float v = (lane < NTILE) ? separt[lane * 512 + bm] : 0.f;
        v = wave_sum(v);
        if (lane == 0) sSE = v;
    }

    float ps = 0.f;
    #pragma unroll
    for (int q = 0; q < NTILE / 2; ++q) {
        int ti = h * (NTILE / 2) + q;
        ps += S_part[((size_t)(b * NTILE + ti) * N_MA + m) * DD + i];
    }
    Sp[h][i] = ps;
    __syncthreads();
    if (t < DD) S_l[t] = Sp[0][t] + Sp[1][t];
    __syncthreads();

    int d = i;
    float acc = 0.f;
    #pragma unroll 8
    for (int q = 0; q < 64; ++q) {
        int ii = h * 64 + q;
        acc += S_l[ii] * W_src[ii * DD + d];
    }
    Wp[h][d] = acc;
    __syncthreads();

    if (t < DD) {
        float er_bm = er[bm];
        float p_kk = __expf(lrelu(2.f * er_bm));
        float Z = sZ + p_kk;
        float invZ = 1.f / Z;
        float bsrc = (Wp[0][d] + Wp[1][d]) * invZ;
        float val = W_edge[d] * (sSE * invZ) + bsrc +
                    feat_dst[(size_t)bm * DD + d] * (p_kk * invZ);
        out[(size_t)bm * DD + d] = 1.f / (1.f + __expf(-val));
    }
}

extern "C" void kernel_launch(void* const* d_in, const int* in_sizes, int n_in,
                              void* d_out, int out_size, void* d_ws, size_t ws_size,
                              hipStream_t stream) {
    const float* h_src = (const float*)d_in[0];
    const float* h_dst = (const float*)d_in[1];
    const float* edge_feat = (const float*)d_in[2];
    const int* adj = (const int*)d_in[3];
    const float* W_src = (const float*)d_in[4];
    const float* W_dst = (const float*)d_in[5];
    const float* W_edge = (const float*)d_in[6];
    const float* attn_l = (const float*)d_in[7];
    const float* attn_r = (const float*)d_in[8];
    float* out = (float*)d_out;

    float* ws = (float*)d_ws;
    float* u = ws;                     // 128
    float* c_we = ws + 128;            // 1
    float* el = ws + 256;              // 8000 (fallback only)
    float* er = ws + 8448;             // 512
    float* feat_dst = ws + 9216;       // 65536
    float* zpart = ws + 75008;         // 16384
    float* separt = ws + 91392;        // 16384
    float* S_part = ws + 107776;       // 2097152

    void* kargs[] = {
        (void*)&h_src, (void*)&h_dst, (void*)&edge_feat, (void*)&adj,
        (void*)&W_src, (void*)&W_dst, (void*)&W_edge, (void*)&attn_l,
        (void*)&attn_r, (void*)&out, (void*)&u, (void*)&c_we, (void*)&er,
        (void*)&feat_dst, (void*)&zpart, (void*)&separt, (void*)&S_part
    };
    hipError_t ce = hipLaunchCooperativeKernel(
        reinterpret_cast<const void*>(&fused_all), dim3(NB * NTILE), dim3(256),
        kargs, 0, stream);
    if (ce != hipSuccess) {
        (void)hipGetLastError();  // clear, fall back to the proven 4-kernel path
        prep_par<<<33, 256, 0, stream>>>(W_src, W_edge, attn_l, u, c_we);
        elfdst_kernel<<<2128, 256, 0, stream>>>(h_src, u, h_dst, W_dst, attn_r,
                                                el, feat_dst, er);
        ab_kernel<<<NB * NTILE, 256, 0, stream>>>(edge_feat, adj, h_src, el, er,
                                                  c_we, S_part, zpart, separt);
        c_kernel<<<NB * N_MA, 256, 0, stream>>>(S_part, zpart, separt, er,
                                                feat_dst, W_src, W_edge, out);
    }
}

// Round 6
// 24.940 us; speedup vs baseline: 5.5785x; 5.5785x over previous
//
#include <hip/hip_runtime.h>
#include <math.h>

#define NB 8
#define N_OP 1000
#define N_MA 64
#define IN_SRC 128
#define IN_DST 64
#define DD 128
#define NEG_SLOPE 0.2f
#define TILE_O 32
#define NTILE 32   // 32*32 = 1024 >= 1000 (tail guarded)
#define HPAD 132   // H tile stride: (132*r+c)%32 = (4r+c)%32 -> <=2-way on el reduce

__device__ __forceinline__ float lrelu(float x) { return x >= 0.f ? x : NEG_SLOPE * x; }

__device__ __forceinline__ float wave_sum(float v) {
    for (int off = 32; off; off >>= 1) v += __shfl_xor(v, off, 64);
    return v;
}

// K1: independent precomputes in one launch.
// blocks [0,33): u[i] = dot(W_src[i,:], attn_l) (one row/wave), blk32.w0 -> c_we
// blocks [33,161): feat_dst row + er (one bm/wave)
__global__ __launch_bounds__(256) void prep_fdst(
    const float* __restrict__ W_src, const float* __restrict__ W_edge,
    const float* __restrict__ attn_l, const float* __restrict__ h_dst,
    const float* __restrict__ W_dst, const float* __restrict__ attn_r,
    float* __restrict__ u, float* __restrict__ c_we,
    float* __restrict__ feat_dst, float* __restrict__ er) {
    int blk = blockIdx.x;
    int lane = threadIdx.x & 63;
    int w = threadIdx.x >> 6;
    if (blk < 33) {
        int task = blk * 4 + w;
        float al0 = attn_l[lane], al1 = attn_l[lane + 64];
        if (task < 128) {
            float part = W_src[task * DD + lane] * al0 +
                         W_src[task * DD + lane + 64] * al1;
            part = wave_sum(part);
            if (lane == 0) u[task] = part;
        } else if (task == 128) {
            float part = W_edge[lane] * al0 + W_edge[lane + 64] * al1;
            part = wave_sum(part);
            if (lane == 0) c_we[0] = part;
        }
    } else {
        int bm = (blk - 33) * 4 + w;     // < 512
        const float* h = h_dst + (size_t)bm * IN_DST;
        float a0 = 0.f, a1 = 0.f;
        #pragma unroll 8
        for (int k = 0; k < IN_DST; ++k) {
            float hk = h[k];
            a0 += hk * W_dst[k * DD + lane];
            a1 += hk * W_dst[k * DD + lane + 64];
        }
        feat_dst[(size_t)bm * DD + lane] = a0;
        feat_dst[(size_t)bm * DD + lane + 64] = a1;
        float r = a0 * attn_r[lane] + a1 * attn_r[lane + 64];
        r = wave_sum(r);
        if (lane == 0) er[bm] = r;
    }
}

// K2: per (b, o-tile): stage H, el in-block (parallel 8-lane reduce from LDS),
// masked exp stats (M=0; logits bounded ~14, safe in f32), partial contraction
// S_part[b,ti,m,i] = sum_o p[o,m]*h_src[b,o,i]
__global__ __launch_bounds__(256) void ab_kernel(
    const float* __restrict__ edge_feat, const int* __restrict__ adj,
    const float* __restrict__ h_src, const float* __restrict__ u,
    const float* __restrict__ er, const float* __restrict__ c_we_p,
    float* __restrict__ S_part, float* __restrict__ zpart,
    float* __restrict__ separt) {
    __shared__ float H_l[TILE_O][HPAD];    // 16.5 KB
    __shared__ float P_l[TILE_O][N_MA];    // 8 KB
    __shared__ float u_l[DD];
    __shared__ float el_l[TILE_O];
    __shared__ float redz[4][64], redse[4][64];

    int blk = blockIdx.x;               // 0..255
    int b = blk >> 5, ti = blk & 31;
    int o0 = ti * TILE_O;
    int nrows = min(TILE_O, N_OP - o0); // 32 (8 for ti==31)
    int t = threadIdx.x;
    float cwe = c_we_p[0];

    // stage H tile (coalesced float4); zero OOB rows
    #pragma unroll
    for (int c = 0; c < 4; ++c) {
        int flat = c * 256 + t;          // 1024 float4 slots = 32 rows x 32
        int row = flat >> 5, col = (flat & 31) * 4;
        float4 hv = make_float4(0.f, 0.f, 0.f, 0.f);
        if (row < nrows)
            hv = *reinterpret_cast<const float4*>(
                h_src + ((size_t)(b * N_OP + o0 + row) * DD + col));
        *reinterpret_cast<float4*>(&H_l[row][col]) = hv;
    }
    if (t < DD) u_l[t] = u[t];
    __syncthreads();

    // el for the 32 tile rows: thread t -> row t>>3, 8-lane-group reduce
    {
        int r = t >> 3, sub = t & 7;
        float part = 0.f;
        #pragma unroll
        for (int q = 0; q < 16; ++q)
            part += H_l[r][sub + 8 * q] * u_l[sub + 8 * q];
        part += __shfl_xor(part, 1, 64);
        part += __shfl_xor(part, 2, 64);
        part += __shfl_xor(part, 4, 64);
        if (sub == 0) el_l[r] = part;
    }
    __syncthreads();

    // phase 1: p + per-tile stats (coalesced adj/ef rows)
    int m = t & 63, og = t >> 6;
    float er_bm = er[b * N_MA + m];
    float z = 0.f, se = 0.f;
    for (int r = og; r < TILE_O; r += 4) {
        float p = 0.f;
        if (r < nrows) {
            size_t eidx = (size_t)(b * N_OP + o0 + r) * N_MA + m;
            if (adj[eidx]) {
                float efv = edge_feat[eidx];
                float v = lrelu(el_l[r] + er_bm + efv * cwe);
                p = __expf(v);
                z += p;
                se += p * efv;
            }
        }
        P_l[r][m] = p;
    }
    redz[og][m] = z;
    redse[og][m] = se;
    __syncthreads();

    if (t < 64) {
        zpart[ti * 512 + b * N_MA + t] =
            redz[0][t] + redz[1][t] + redz[2][t] + redz[3][t];
    } else if (t < 128) {
        int mm = t - 64;
        separt[ti * 512 + b * N_MA + mm] =
            redse[0][mm] + redse[1][mm] + redse[2][mm] + redse[3][mm];
    }

    // phase 2: S_part[m][i] = sum_k P_l[k][m] * H_l[k][i]
    int i4 = t & 31, mg = t >> 5;
    float acc[8][4];
    #pragma unroll
    for (int a = 0; a < 8; ++a)
        #pragma unroll
        for (int c = 0; c < 4; ++c) acc[a][c] = 0.f;

    for (int k = 0; k < TILE_O; ++k) {
        float4 hv = *reinterpret_cast<const float4*>(&H_l[k][i4 * 4]);
        float4 pa = *reinterpret_cast<const float4*>(&P_l[k][mg * 8]);
        float4 pb = *reinterpret_cast<const float4*>(&P_l[k][mg * 8 + 4]);
        float hh[4] = {hv.x, hv.y, hv.z, hv.w};
        float pp[8] = {pa.x, pa.y, pa.z, pa.w, pb.x, pb.y, pb.z, pb.w};
        #pragma unroll
        for (int mm = 0; mm < 8; ++mm)
            #pragma unroll
            for (int ii = 0; ii < 4; ++ii)
                acc[mm][ii] += pp[mm] * hh[ii];
    }

    #pragma unroll
    for (int mm = 0; mm < 8; ++mm) {
        size_t off = ((size_t)(b * NTILE + ti) * N_MA + mg * 8 + mm) * DD + i4 * 4;
        *reinterpret_cast<float4*>(S_part + off) =
            make_float4(acc[mm][0], acc[mm][1], acc[mm][2], acc[mm][3]);
    }
}

// K3: per (b,m): sum partials, matvec with W_src, epilogue sigmoid
__global__ __launch_bounds__(256) void c_kernel(
    const float* __restrict__ S_part, const float* __restrict__ zpart,
    const float* __restrict__ separt, const float* __restrict__ er,
    const float* __restrict__ feat_dst, const float* __restrict__ W_src,
    const float* __restrict__ W_edge, float* __restrict__ out) {
    __shared__ float Sp[2][DD];
    __shared__ float S_l[DD];
    __shared__ float Wp[2][DD];
    __shared__ float sZ, sSE;

    int bm = blockIdx.x;
    int b = bm >> 6, m = bm & 63;
    int t = threadIdx.x;
    int i = t & 127, h = t >> 7;
    int lane = t & 63, w = t >> 6;

    if (w == 0) {
        float v = (lane < NTILE) ? zpart[lane * 512 + bm] : 0.f;
        v = wave_sum(v);
        if (lane == 0) sZ = v;
    } else if (w == 1) {
        float v = (lane < NTILE) ? separt[lane * 512 + bm] : 0.f;
        v = wave_sum(v);
        if (lane == 0) sSE = v;
    }

    float ps = 0.f;
    #pragma unroll
    for (int q = 0; q < NTILE / 2; ++q) {
        int ti = h * (NTILE / 2) + q;
        ps += S_part[((size_t)(b * NTILE + ti) * N_MA + m) * DD + i];
    }
    Sp[h][i] = ps;
    __syncthreads();
    if (t < DD) S_l[t] = Sp[0][t] + Sp[1][t];
    __syncthreads();

    float acc = 0.f;
    #pragma unroll 8
    for (int q = 0; q < 64; ++q) {
        int ii = h * 64 + q;
        acc += S_l[ii] * W_src[ii * DD + i];
    }
    Wp[h][i] = acc;
    __syncthreads();

    if (t < DD) {
        float er_bm = er[bm];
        float p_kk = __expf(lrelu(2.f * er_bm));
        float Z = sZ + p_kk;
        float invZ = 1.f / Z;
        float bsrc = (Wp[0][i] + Wp[1][i]) * invZ;
        float val = W_edge[i] * (sSE * invZ) + bsrc +
                    feat_dst[(size_t)bm * DD + i] * (p_kk * invZ);
        out[(size_t)bm * DD + i] = 1.f / (1.f + __expf(-val));
    }
}

extern "C" void kernel_launch(void* const* d_in, const int* in_sizes, int n_in,
                              void* d_out, int out_size, void* d_ws, size_t ws_size,
                              hipStream_t stream) {
    const float* h_src = (const float*)d_in[0];
    const float* h_dst = (const float*)d_in[1];
    const float* edge_feat = (const float*)d_in[2];
    const int* adj = (const int*)d_in[3];
    const float* W_src = (const float*)d_in[4];
    const float* W_dst = (const float*)d_in[5];
    const float* W_edge = (const float*)d_in[6];
    const float* attn_l = (const float*)d_in[7];
    const float* attn_r = (const float*)d_in[8];
    float* out = (float*)d_out;

    float* ws = (float*)d_ws;
    float* u = ws;                     // 128
    float* c_we = ws + 128;            // 1
    float* er = ws + 8448;             // 512
    float* feat_dst = ws + 9216;       // 65536
    float* zpart = ws + 75008;         // 16384
    float* separt = ws + 91392;        // 16384
    float* S_part = ws + 107776;       // 2097152

    prep_fdst<<<161, 256, 0, stream>>>(W_src, W_edge, attn_l, h_dst, W_dst,
                                       attn_r, u, c_we, feat_dst, er);
    ab_kernel<<<NB * NTILE, 256, 0, stream>>>(edge_feat, adj, h_src, u, er,
                                              c_we, S_part, zpart, separt);
    c_kernel<<<NB * N_MA, 256, 0, stream>>>(S_part, zpart, separt, er,
                                            feat_dst, W_src, W_edge, out);
}